// Round 4
// baseline (832.681 us; speedup 1.0000x reference)
//
#include <hip/hip_runtime.h>

#define IN_C   512
#define HID_C  256
#define OUT_C  64
#define KSTEPS 10

typedef __attribute__((ext_vector_type(8))) short bf16x8;
typedef __attribute__((ext_vector_type(4))) float f32x4;

__device__ __forceinline__ uint f2bf(float f) {
    uint u = __float_as_uint(f);
    return (u + 0x7fffu + ((u >> 16) & 1u)) >> 16;   // RNE to bf16
}
__device__ __forceinline__ float bfl(uint u) { return __uint_as_float(u << 16); }
__device__ __forceinline__ float bfh(uint u) { return __uint_as_float(u & 0xffff0000u); }

// ---------------------------------------------------------------------------
// CSR build: histogram by dst, exclusive scan, scatter (src, norm) pairs.
// ---------------------------------------------------------------------------
__global__ void k_init(int* __restrict__ cnt, int* __restrict__ fill, int n) {
    int i = blockIdx.x * blockDim.x + threadIdx.x;
    if (i < n) { cnt[i] = 0; fill[i] = 0; }
}

__global__ void k_hist(const int* __restrict__ ei, int* __restrict__ cnt, int E) {
    int e = blockIdx.x * blockDim.x + threadIdx.x;
    if (e < E) atomicAdd(&cnt[ei[E + e]], 1);
}

__global__ void k_dinv(const int* __restrict__ cnt, float* __restrict__ dinv, int n) {
    int i = blockIdx.x * blockDim.x + threadIdx.x;
    if (i < n) dinv[i] = rsqrtf((float)cnt[i] + 1.0f);   // deg includes self loop
}

__global__ void k_scan1(const int* __restrict__ cnt, int* __restrict__ rowptr,
                        int* __restrict__ bsum, int n) {
    __shared__ int sh[256];
    int i = blockIdx.x * 256 + threadIdx.x;
    int v = (i < n) ? cnt[i] : 0;
    sh[threadIdx.x] = v;
    __syncthreads();
    for (int off = 1; off < 256; off <<= 1) {
        int t = (threadIdx.x >= off) ? sh[threadIdx.x - off] : 0;
        __syncthreads();
        sh[threadIdx.x] += t;
        __syncthreads();
    }
    if (i < n) rowptr[i + 1] = sh[threadIdx.x];
    if (threadIdx.x == 255) bsum[blockIdx.x] = sh[255];
}

__global__ void k_scan2(int* __restrict__ bsum, int nb) {
    __shared__ int sh[512];
    int t = threadIdx.x;
    int v = (t < nb) ? bsum[t] : 0;
    sh[t] = v;
    __syncthreads();
    for (int off = 1; off < 512; off <<= 1) {
        int u = (t >= off) ? sh[t - off] : 0;
        __syncthreads();
        sh[t] += u;
        __syncthreads();
    }
    int ex = (t == 0) ? 0 : sh[t - 1];
    if (t < nb) bsum[t] = ex;
}

__global__ void k_scan3(int* __restrict__ rowptr, const int* __restrict__ bsum, int n) {
    int i = blockIdx.x * blockDim.x + threadIdx.x;
    if (i < n) rowptr[i + 1] += bsum[i >> 8];
    if (i == 0) rowptr[0] = 0;
}

__global__ void k_scatter(const int* __restrict__ ei, const float* __restrict__ dinv,
                          const int* __restrict__ rowptr, int* __restrict__ fill,
                          int2* __restrict__ edges, int E) {
    int e = blockIdx.x * blockDim.x + threadIdx.x;
    if (e < E) {
        int s = ei[e], d = ei[E + e];
        float nv = dinv[s] * dinv[d];
        int pos = rowptr[d] + atomicAdd(&fill[d], 1);
        edges[pos] = make_int2(s, __float_as_int(nv));
    }
}

// f32 -> bf16 conversion (W1, row-major)
__global__ void k_cvt(const float* __restrict__ src, ushort* __restrict__ dst, int n) {
    int i = blockIdx.x * blockDim.x + threadIdx.x;
    if (i < n) dst[i] = (ushort)f2bf(src[i]);
}

// W2 -> bf16, k-block-major: w2kt[kb][n][8], kb = hidden/8. Coalesced B-frag reads.
__global__ void k_cvtw2(const float* __restrict__ W2, ushort* __restrict__ w2kt) {
    int i = blockIdx.x * blockDim.x + threadIdx.x;
    if (i < OUT_C * HID_C) {
        int o = i >> 8;       // W2 row (out channel) 0..63
        int c = i & 255;      // hidden idx 0..255
        int kb = c >> 3, j = c & 7;
        w2kt[((size_t)(kb * 64 + o)) * 8 + j] = (ushort)f2bf(W2[i]);
    }
}

// ---------------------------------------------------------------------------
// Fused MFMA MLP: h2 = relu(x@W1^T + b1) @ W2^T + b2  (bf16 in, fp32 accum)
// 4 waves, BM=64. Stage1: wave w -> hidden cols [64w,64w+64), BK=64,
// x/W1 tiles register-prefetched one K-step ahead (overlap with MFMA).
// h1 -> LDS bf16 swizzled. Stage2: B fragments from w2kt (coalesced global).
// LDS 40KB -> 4 blocks/CU.
// ---------------------------------------------------------------------------
__global__ __launch_bounds__(256, 4) void k_mlp(
    const float* __restrict__ x, const ushort* __restrict__ W1b,
    const float* __restrict__ b1, const ushort* __restrict__ w2kt,
    const float* __restrict__ b2, const float* __restrict__ temp,
    ushort* __restrict__ h, float* __restrict__ out, int n)
{
    __shared__ uint4 smem4[2560];            // 40 KB
    char* smem = (char*)smem4;

    const int tid = threadIdx.x;
    const int lane = tid & 63;
    const int w    = tid >> 6;        // wave 0..3
    const int l15  = lane & 15;
    const int l4   = lane >> 4;       // 0..3
    const int row0 = blockIdx.x * 64;

    f32x4 acc[4][4];                  // [rf][nf]
#pragma unroll
    for (int i = 0; i < 4; ++i)
#pragma unroll
        for (int j = 0; j < 4; ++j) acc[i][j] = (f32x4){0.f, 0.f, 0.f, 0.f};

    // register prefetch buffers
    float4 px[4];
    uint4  pw[8];
#pragma unroll
    for (int it = 0; it < 4; ++it) {
        int f = tid + it * 256, r = f >> 4, c4 = f & 15;
        int gr = row0 + r; if (gr >= n) gr = n - 1;
        px[it] = *(const float4*)(x + (size_t)gr * IN_C + c4 * 4);
    }
#pragma unroll
    for (int it = 0; it < 8; ++it) {
        int m = tid + it * 256, nn = m >> 3, bq = m & 7;
        pw[it] = *(const uint4*)(W1b + (size_t)nn * IN_C + bq * 8);
    }

    for (int k0 = 0; k0 < IN_C; k0 += 64) {
        // drain prefetched tiles into LDS (x converted to bf16), swizzled
#pragma unroll
        for (int it = 0; it < 4; ++it) {
            int f = tid + it * 256, r = f >> 4, c4 = f & 15;
            uint p0 = f2bf(px[it].x) | (f2bf(px[it].y) << 16);
            uint p1 = f2bf(px[it].z) | (f2bf(px[it].w) << 16);
            int boff = (c4 * 8) ^ ((r & 7) << 4);
            *(uint2*)(smem + 32768 + r * 128 + boff) = make_uint2(p0, p1);
        }
#pragma unroll
        for (int it = 0; it < 8; ++it) {
            int m = tid + it * 256, nn = m >> 3, bq = m & 7;
            int bd = bq ^ (nn & 7);
            *(uint4*)(smem + nn * 128 + (bd << 4)) = pw[it];
        }
        __syncthreads();

        // issue next tile's global loads (overlap with MFMA below)
        if (k0 + 64 < IN_C) {
#pragma unroll
            for (int it = 0; it < 4; ++it) {
                int f = tid + it * 256, r = f >> 4, c4 = f & 15;
                int gr = row0 + r; if (gr >= n) gr = n - 1;
                px[it] = *(const float4*)(x + (size_t)gr * IN_C + (k0 + 64) + c4 * 4);
            }
#pragma unroll
            for (int it = 0; it < 8; ++it) {
                int m = tid + it * 256, nn = m >> 3, bq = m & 7;
                pw[it] = *(const uint4*)(W1b + (size_t)nn * IN_C + (k0 + 64) + bq * 8);
            }
        }

#pragma unroll
        for (int kk = 0; kk < 2; ++kk) {
            bf16x8 af[4], bfr[4];
            int kb = kk * 4 + l4;             // 16B-block in k
#pragma unroll
            for (int rf = 0; rf < 4; ++rf) {
                int r = rf * 16 + l15;
                af[rf] = *(const bf16x8*)(smem + 32768 + r * 128 + ((kb ^ (r & 7)) << 4));
            }
#pragma unroll
            for (int nf = 0; nf < 4; ++nf) {
                int nn = w * 64 + nf * 16 + l15;
                bfr[nf] = *(const bf16x8*)(smem + nn * 128 + ((kb ^ (nn & 7)) << 4));
            }
#pragma unroll
            for (int rf = 0; rf < 4; ++rf)
#pragma unroll
                for (int nf = 0; nf < 4; ++nf)
                    acc[rf][nf] = __builtin_amdgcn_mfma_f32_16x16x32_bf16(
                        af[rf], bfr[nf], acc[rf][nf], 0, 0, 0);
        }
        __syncthreads();
    }

    // bias + relu -> h1s bf16 swizzled at 0 (overwrites w1s; barrier done)
    float bias1[4];
#pragma unroll
    for (int nf = 0; nf < 4; ++nf) bias1[nf] = b1[w * 64 + nf * 16 + l15];
#pragma unroll
    for (int rf = 0; rf < 4; ++rf)
#pragma unroll
        for (int nf = 0; nf < 4; ++nf)
#pragma unroll
            for (int j = 0; j < 4; ++j) {
                int r = rf * 16 + l4 * 4 + j;
                int c = w * 64 + nf * 16 + l15;
                float v = fmaxf(acc[rf][nf][j] + bias1[nf], 0.f);
                int byte = r * 512 + ((((c >> 3) ^ (r & 7))) << 4) + (c & 7) * 2;
                *(ushort*)(smem + byte) = (ushort)f2bf(v);
            }
    __syncthreads();

    // stage 2: rows slab per wave, K=256; B fragments from w2kt (coalesced)
    f32x4 acc2[4];
#pragma unroll
    for (int nf = 0; nf < 4; ++nf) acc2[nf] = (f32x4){0.f, 0.f, 0.f, 0.f};
#pragma unroll
    for (int kk = 0; kk < 8; ++kk) {
        int r = w * 16 + l15;
        int kb = kk * 4 + l4;
        bf16x8 a = *(const bf16x8*)(smem + r * 512 + ((kb ^ (r & 7)) << 4));
#pragma unroll
        for (int nf = 0; nf < 4; ++nf) {
            bf16x8 bb = *(const bf16x8*)(w2kt + ((size_t)kb * 64 + nf * 16 + l15) * 8);
            acc2[nf] = __builtin_amdgcn_mfma_f32_16x16x32_bf16(a, bb, acc2[nf], 0, 0, 0);
        }
    }

    float t0 = temp[0];
#pragma unroll
    for (int nf = 0; nf < 4; ++nf) {
        int c = nf * 16 + l15;
        float bias = b2[c];
#pragma unroll
        for (int j = 0; j < 4; ++j) {
            int gr = row0 + w * 16 + l4 * 4 + j;
            if (gr < n) {
                float v = acc2[nf][j] + bias;
                h[(size_t)gr * OUT_C + c]   = (ushort)f2bf(v);
                out[(size_t)gr * OUT_C + c] = t0 * v;
            }
        }
    }
}

// ---------------------------------------------------------------------------
// One propagation step: one 8-lane GROUP per dst node (8 nodes/wave).
// Group iterates its own edge list (unroll x2, 2 gathers in flight) -> no
// cross-lane reduction at all. On even steps, folds out += gp*cur + gc*acc
// (cur row already loaded for the self-loop term).
// ---------------------------------------------------------------------------
__global__ __launch_bounds__(256) void k_prop(
    const int* __restrict__ rowptr, const int2* __restrict__ edges,
    const ushort* __restrict__ cur, ushort* __restrict__ nxt,
    float* __restrict__ out, const float* __restrict__ dinv,
    const float* __restrict__ temp, int kcur, int do_rmw, int do_nxt, int n)
{
    const int lane = threadIdx.x & 63;
    const int g    = lane >> 3;          // group 0..7 = node slot
    const int sl   = lane & 7;           // channel octet
    const int wid  = (blockIdx.x * blockDim.x + threadIdx.x) >> 6;
    const int nw   = (gridDim.x * blockDim.x) >> 6;
    const float gc = temp[kcur];
    const float gp = temp[kcur - 1];

    for (int base = wid * 8; base < n; base += nw * 8) {
        int d = base + g;
        bool act = d < n;
        int dd = act ? d : (n - 1);
        int b = rowptr[dd];
        int en = act ? rowptr[dd + 1] : b;
        float di = dinv[dd];
        size_t rowoff = (size_t)dd * OUT_C + sl * 8;

        uint4 sraw = *(const uint4*)(cur + rowoff);
        float c0 = bfl(sraw.x), c1 = bfh(sraw.x), c2 = bfl(sraw.y), c3 = bfh(sraw.y),
              c4 = bfl(sraw.z), c5 = bfh(sraw.z), c6 = bfl(sraw.w), c7 = bfh(sraw.w);
        float s = di * di;
        float a0 = s * c0, a1 = s * c1, a2 = s * c2, a3 = s * c3,
              a4 = s * c4, a5 = s * c5, a6 = s * c6, a7 = s * c7;

        int i = b;
        for (; i + 2 <= en; i += 2) {
            int2 e0 = edges[i], e1 = edges[i + 1];
            uint4 r0 = *(const uint4*)(cur + (size_t)e0.x * OUT_C + sl * 8);
            uint4 r1 = *(const uint4*)(cur + (size_t)e1.x * OUT_C + sl * 8);
            float w0 = __int_as_float(e0.y), w1 = __int_as_float(e1.y);
            a0 = fmaf(w0, bfl(r0.x), a0); a1 = fmaf(w0, bfh(r0.x), a1);
            a2 = fmaf(w0, bfl(r0.y), a2); a3 = fmaf(w0, bfh(r0.y), a3);
            a4 = fmaf(w0, bfl(r0.z), a4); a5 = fmaf(w0, bfh(r0.z), a5);
            a6 = fmaf(w0, bfl(r0.w), a6); a7 = fmaf(w0, bfh(r0.w), a7);
            a0 = fmaf(w1, bfl(r1.x), a0); a1 = fmaf(w1, bfh(r1.x), a1);
            a2 = fmaf(w1, bfl(r1.y), a2); a3 = fmaf(w1, bfh(r1.y), a3);
            a4 = fmaf(w1, bfl(r1.z), a4); a5 = fmaf(w1, bfh(r1.z), a5);
            a6 = fmaf(w1, bfl(r1.w), a6); a7 = fmaf(w1, bfh(r1.w), a7);
        }
        if (i < en) {
            int2 e = edges[i];
            uint4 r0 = *(const uint4*)(cur + (size_t)e.x * OUT_C + sl * 8);
            float w0 = __int_as_float(e.y);
            a0 = fmaf(w0, bfl(r0.x), a0); a1 = fmaf(w0, bfh(r0.x), a1);
            a2 = fmaf(w0, bfl(r0.y), a2); a3 = fmaf(w0, bfh(r0.y), a3);
            a4 = fmaf(w0, bfl(r0.z), a4); a5 = fmaf(w0, bfh(r0.z), a5);
            a6 = fmaf(w0, bfl(r0.w), a6); a7 = fmaf(w0, bfh(r0.w), a7);
        }

        if (act) {
            if (do_nxt) {
                uint4 pk;
                pk.x = f2bf(a0) | (f2bf(a1) << 16);
                pk.y = f2bf(a2) | (f2bf(a3) << 16);
                pk.z = f2bf(a4) | (f2bf(a5) << 16);
                pk.w = f2bf(a6) | (f2bf(a7) << 16);
                *(uint4*)(nxt + rowoff) = pk;
            }
            if (do_rmw) {
                float4* op = (float4*)(out + rowoff);
                float4 v0 = op[0], v1 = op[1];
                v0.x += gp * c0 + gc * a0; v0.y += gp * c1 + gc * a1;
                v0.z += gp * c2 + gc * a2; v0.w += gp * c3 + gc * a3;
                v1.x += gp * c4 + gc * a4; v1.y += gp * c5 + gc * a5;
                v1.z += gp * c6 + gc * a6; v1.w += gp * c7 + gc * a7;
                op[0] = v0; op[1] = v1;
            }
        }
    }
}

// ---------------------------------------------------------------------------
extern "C" void kernel_launch(void* const* d_in, const int* in_sizes, int n_in,
                              void* d_out, int out_size, void* d_ws, size_t ws_size,
                              hipStream_t stream)
{
    const float* x    = (const float*)d_in[0];
    const int*   ei   = (const int*)d_in[1];
    const float* W1   = (const float*)d_in[2];
    const float* b1   = (const float*)d_in[3];
    const float* W2   = (const float*)d_in[4];
    const float* b2   = (const float*)d_in[5];
    const float* temp = (const float*)d_in[6];
    float* out = (float*)d_out;

    const int N = in_sizes[0] / IN_C;
    const int E = in_sizes[1] / 2;

    // workspace layout
    char* ws = (char*)d_ws;
    ushort* bufA  = (ushort*)ws;                       // N*64 bf16
    ushort* bufB  = bufA + (size_t)N * OUT_C;          // N*64 bf16
    int2*   edges = (int2*)(bufB + (size_t)N * OUT_C); // E int2
    ushort* W1b   = (ushort*)(edges + E);
    ushort* w2kt  = W1b + HID_C * IN_C;
    float*  dinv  = (float*)(w2kt + OUT_C * HID_C);
    int*    cnt    = (int*)(dinv + N);
    int*    fill   = cnt + N;
    int*    rowptr = fill + N;
    int*    bsum   = rowptr + (N + 16);

    const int nbN = (N + 255) / 256;
    const int nbE = (E + 255) / 256;

    k_init   <<<nbN, 256, 0, stream>>>(cnt, fill, N);
    k_hist   <<<nbE, 256, 0, stream>>>(ei, cnt, E);
    k_dinv   <<<nbN, 256, 0, stream>>>(cnt, dinv, N);
    k_scan1  <<<nbN, 256, 0, stream>>>(cnt, rowptr, bsum, N);
    k_scan2  <<<1,   512, 0, stream>>>(bsum, nbN);
    k_scan3  <<<nbN, 256, 0, stream>>>(rowptr, bsum, N);
    k_scatter<<<nbE, 256, 0, stream>>>(ei, dinv, rowptr, fill, edges, E);
    k_cvt    <<<(HID_C * IN_C + 255) / 256, 256, 0, stream>>>(W1, W1b, HID_C * IN_C);
    k_cvtw2  <<<(OUT_C * HID_C + 255) / 256, 256, 0, stream>>>(W2, w2kt);

    k_mlp<<<(N + 63) / 64, 256, 0, stream>>>(x, W1b, b1, w2kt, b2, temp, bufA, out, N);

    ushort* cur = bufA;
    ushort* nxt = bufB;
    for (int k = 1; k <= KSTEPS; ++k) {
        int do_rmw = (k % 2 == 0) ? 1 : 0;
        int do_nxt = (k < KSTEPS) ? 1 : 0;
        k_prop<<<2048, 256, 0, stream>>>(rowptr, edges, cur, nxt, out, dinv,
                                         temp, k, do_rmw, do_nxt, N);
        ushort* t = cur; cur = nxt; nxt = t;
    }
}

// Round 5
// 756.691 us; speedup vs baseline: 1.1004x; 1.1004x over previous
//
#include <hip/hip_runtime.h>

#define IN_C   512
#define HID_C  256
#define OUT_C  64
#define KSTEPS 10

typedef __attribute__((ext_vector_type(8))) short bf16x8;
typedef __attribute__((ext_vector_type(4))) float f32x4;

__device__ __forceinline__ uint f2bf(float f) {
    uint u = __float_as_uint(f);
    return (u + 0x7fffu + ((u >> 16) & 1u)) >> 16;   // RNE to bf16
}
__device__ __forceinline__ float bfl(uint u) { return __uint_as_float(u << 16); }
__device__ __forceinline__ float bfh(uint u) { return __uint_as_float(u & 0xffff0000u); }

// ---------------------------------------------------------------------------
// CSR build: histogram by dst, exclusive scan, scatter (src, norm) pairs.
// ---------------------------------------------------------------------------
__global__ void k_init(int* __restrict__ cnt, int* __restrict__ fill, int n) {
    int i = blockIdx.x * blockDim.x + threadIdx.x;
    if (i < n) { cnt[i] = 0; fill[i] = 0; }
}

__global__ void k_hist(const int* __restrict__ ei, int* __restrict__ cnt, int E) {
    int e = blockIdx.x * blockDim.x + threadIdx.x;
    if (e < E) atomicAdd(&cnt[ei[E + e]], 1);
}

__global__ void k_dinv(const int* __restrict__ cnt, float* __restrict__ dinv, int n) {
    int i = blockIdx.x * blockDim.x + threadIdx.x;
    if (i < n) dinv[i] = rsqrtf((float)cnt[i] + 1.0f);   // deg includes self loop
}

__global__ void k_scan1(const int* __restrict__ cnt, int* __restrict__ rowptr,
                        int* __restrict__ bsum, int n) {
    __shared__ int sh[256];
    int i = blockIdx.x * 256 + threadIdx.x;
    int v = (i < n) ? cnt[i] : 0;
    sh[threadIdx.x] = v;
    __syncthreads();
    for (int off = 1; off < 256; off <<= 1) {
        int t = (threadIdx.x >= off) ? sh[threadIdx.x - off] : 0;
        __syncthreads();
        sh[threadIdx.x] += t;
        __syncthreads();
    }
    if (i < n) rowptr[i + 1] = sh[threadIdx.x];
    if (threadIdx.x == 255) bsum[blockIdx.x] = sh[255];
}

__global__ void k_scan2(int* __restrict__ bsum, int nb) {
    __shared__ int sh[512];
    int t = threadIdx.x;
    int v = (t < nb) ? bsum[t] : 0;
    sh[t] = v;
    __syncthreads();
    for (int off = 1; off < 512; off <<= 1) {
        int u = (t >= off) ? sh[t - off] : 0;
        __syncthreads();
        sh[t] += u;
        __syncthreads();
    }
    int ex = (t == 0) ? 0 : sh[t - 1];
    if (t < nb) bsum[t] = ex;
}

__global__ void k_scan3(int* __restrict__ rowptr, const int* __restrict__ bsum, int n) {
    int i = blockIdx.x * blockDim.x + threadIdx.x;
    if (i < n) rowptr[i + 1] += bsum[i >> 8];
    if (i == 0) rowptr[0] = 0;
}

__global__ void k_scatter(const int* __restrict__ ei, const float* __restrict__ dinv,
                          const int* __restrict__ rowptr, int* __restrict__ fill,
                          int2* __restrict__ edges, int E) {
    int e = blockIdx.x * blockDim.x + threadIdx.x;
    if (e < E) {
        int s = ei[e], d = ei[E + e];
        float nv = dinv[s] * dinv[d];
        int pos = rowptr[d] + atomicAdd(&fill[d], 1);
        edges[pos] = make_int2(s, __float_as_int(nv));
    }
}

// f32 -> bf16 conversion (W1, row-major)
__global__ void k_cvt(const float* __restrict__ src, ushort* __restrict__ dst, int n) {
    int i = blockIdx.x * blockDim.x + threadIdx.x;
    if (i < n) dst[i] = (ushort)f2bf(src[i]);
}

// W2 -> bf16, k-block-major: w2kt[kb][n][8], kb = hidden/8. Coalesced B-frag reads.
__global__ void k_cvtw2(const float* __restrict__ W2, ushort* __restrict__ w2kt) {
    int i = blockIdx.x * blockDim.x + threadIdx.x;
    if (i < OUT_C * HID_C) {
        int o = i >> 8;       // W2 row (out channel) 0..63
        int c = i & 255;      // hidden idx 0..255
        int kb = c >> 3, j = c & 7;
        w2kt[((size_t)(kb * 64 + o)) * 8 + j] = (ushort)f2bf(W2[i]);
    }
}

// ---------------------------------------------------------------------------
// Fused MFMA MLP: h2 = relu(x@W1^T + b1) @ W2^T + b2  (bf16 in, fp32 accum)
// 4 waves, BM=64. Stage1: wave w -> hidden cols [64w,64w+64), BK=64,
// x/W1 tiles register-prefetched one K-step ahead (overlap with MFMA).
// h1 -> LDS bf16 swizzled. Stage2: B fragments from w2kt (coalesced global).
// __launch_bounds__(256,2): VGPR cap 256 — prefetch state (~48 VGPR) MUST
// NOT spill (round-4 lesson: (256,4) capped at 64 VGPR -> 900 MB scratch).
// ---------------------------------------------------------------------------
__global__ __launch_bounds__(256, 2) void k_mlp(
    const float* __restrict__ x, const ushort* __restrict__ W1b,
    const float* __restrict__ b1, const ushort* __restrict__ w2kt,
    const float* __restrict__ b2, const float* __restrict__ temp,
    ushort* __restrict__ h, float* __restrict__ out, int n)
{
    __shared__ uint4 smem4[2560];            // 40 KB
    char* smem = (char*)smem4;

    const int tid = threadIdx.x;
    const int lane = tid & 63;
    const int w    = tid >> 6;        // wave 0..3
    const int l15  = lane & 15;
    const int l4   = lane >> 4;       // 0..3
    const int row0 = blockIdx.x * 64;

    f32x4 acc[4][4];                  // [rf][nf]
#pragma unroll
    for (int i = 0; i < 4; ++i)
#pragma unroll
        for (int j = 0; j < 4; ++j) acc[i][j] = (f32x4){0.f, 0.f, 0.f, 0.f};

    // register prefetch buffers
    float4 px[4];
    uint4  pw[8];
#pragma unroll
    for (int it = 0; it < 4; ++it) {
        int f = tid + it * 256, r = f >> 4, c4 = f & 15;
        int gr = row0 + r; if (gr >= n) gr = n - 1;
        px[it] = *(const float4*)(x + (size_t)gr * IN_C + c4 * 4);
    }
#pragma unroll
    for (int it = 0; it < 8; ++it) {
        int m = tid + it * 256, nn = m >> 3, bq = m & 7;
        pw[it] = *(const uint4*)(W1b + (size_t)nn * IN_C + bq * 8);
    }

    for (int k0 = 0; k0 < IN_C; k0 += 64) {
        // drain prefetched tiles into LDS (x converted to bf16), swizzled
#pragma unroll
        for (int it = 0; it < 4; ++it) {
            int f = tid + it * 256, r = f >> 4, c4 = f & 15;
            uint p0 = f2bf(px[it].x) | (f2bf(px[it].y) << 16);
            uint p1 = f2bf(px[it].z) | (f2bf(px[it].w) << 16);
            int boff = (c4 * 8) ^ ((r & 7) << 4);
            *(uint2*)(smem + 32768 + r * 128 + boff) = make_uint2(p0, p1);
        }
#pragma unroll
        for (int it = 0; it < 8; ++it) {
            int m = tid + it * 256, nn = m >> 3, bq = m & 7;
            int bd = bq ^ (nn & 7);
            *(uint4*)(smem + nn * 128 + (bd << 4)) = pw[it];
        }
        __syncthreads();

        // issue next tile's global loads (overlap with MFMA below)
        if (k0 + 64 < IN_C) {
#pragma unroll
            for (int it = 0; it < 4; ++it) {
                int f = tid + it * 256, r = f >> 4, c4 = f & 15;
                int gr = row0 + r; if (gr >= n) gr = n - 1;
                px[it] = *(const float4*)(x + (size_t)gr * IN_C + (k0 + 64) + c4 * 4);
            }
#pragma unroll
            for (int it = 0; it < 8; ++it) {
                int m = tid + it * 256, nn = m >> 3, bq = m & 7;
                pw[it] = *(const uint4*)(W1b + (size_t)nn * IN_C + (k0 + 64) + bq * 8);
            }
        }

#pragma unroll
        for (int kk = 0; kk < 2; ++kk) {
            bf16x8 af[4], bfr[4];
            int kb = kk * 4 + l4;             // 16B-block in k
#pragma unroll
            for (int rf = 0; rf < 4; ++rf) {
                int r = rf * 16 + l15;
                af[rf] = *(const bf16x8*)(smem + 32768 + r * 128 + ((kb ^ (r & 7)) << 4));
            }
#pragma unroll
            for (int nf = 0; nf < 4; ++nf) {
                int nn = w * 64 + nf * 16 + l15;
                bfr[nf] = *(const bf16x8*)(smem + nn * 128 + ((kb ^ (nn & 7)) << 4));
            }
#pragma unroll
            for (int rf = 0; rf < 4; ++rf)
#pragma unroll
                for (int nf = 0; nf < 4; ++nf)
                    acc[rf][nf] = __builtin_amdgcn_mfma_f32_16x16x32_bf16(
                        af[rf], bfr[nf], acc[rf][nf], 0, 0, 0);
        }
        __syncthreads();
    }

    // bias + relu -> h1s bf16 swizzled at 0 (overwrites w1s; barrier done)
    float bias1[4];
#pragma unroll
    for (int nf = 0; nf < 4; ++nf) bias1[nf] = b1[w * 64 + nf * 16 + l15];
#pragma unroll
    for (int rf = 0; rf < 4; ++rf)
#pragma unroll
        for (int nf = 0; nf < 4; ++nf)
#pragma unroll
            for (int j = 0; j < 4; ++j) {
                int r = rf * 16 + l4 * 4 + j;
                int c = w * 64 + nf * 16 + l15;
                float v = fmaxf(acc[rf][nf][j] + bias1[nf], 0.f);
                int byte = r * 512 + ((((c >> 3) ^ (r & 7))) << 4) + (c & 7) * 2;
                *(ushort*)(smem + byte) = (ushort)f2bf(v);
            }
    __syncthreads();

    // stage 2: rows slab per wave, K=256; B fragments from w2kt (coalesced)
    f32x4 acc2[4];
#pragma unroll
    for (int nf = 0; nf < 4; ++nf) acc2[nf] = (f32x4){0.f, 0.f, 0.f, 0.f};
#pragma unroll
    for (int kk = 0; kk < 8; ++kk) {
        int r = w * 16 + l15;
        int kb = kk * 4 + l4;
        bf16x8 a = *(const bf16x8*)(smem + r * 512 + ((kb ^ (r & 7)) << 4));
#pragma unroll
        for (int nf = 0; nf < 4; ++nf) {
            bf16x8 bb = *(const bf16x8*)(w2kt + ((size_t)kb * 64 + nf * 16 + l15) * 8);
            acc2[nf] = __builtin_amdgcn_mfma_f32_16x16x32_bf16(a, bb, acc2[nf], 0, 0, 0);
        }
    }

    float t0 = temp[0];
#pragma unroll
    for (int nf = 0; nf < 4; ++nf) {
        int c = nf * 16 + l15;
        float bias = b2[c];
#pragma unroll
        for (int j = 0; j < 4; ++j) {
            int gr = row0 + w * 16 + l4 * 4 + j;
            if (gr < n) {
                float v = acc2[nf][j] + bias;
                h[(size_t)gr * OUT_C + c]   = (ushort)f2bf(v);
                out[(size_t)gr * OUT_C + c] = t0 * v;
            }
        }
    }
}

// ---------------------------------------------------------------------------
// One propagation step: one 8-lane GROUP per dst node (8 nodes/wave).
// Group iterates its own edge list (unroll x2, 2 gathers in flight) -> no
// cross-lane reduction at all. On even steps, folds out += gp*cur + gc*acc
// (cur row already loaded for the self-loop term).
// ---------------------------------------------------------------------------
__global__ __launch_bounds__(256) void k_prop(
    const int* __restrict__ rowptr, const int2* __restrict__ edges,
    const ushort* __restrict__ cur, ushort* __restrict__ nxt,
    float* __restrict__ out, const float* __restrict__ dinv,
    const float* __restrict__ temp, int kcur, int do_rmw, int do_nxt, int n)
{
    const int lane = threadIdx.x & 63;
    const int g    = lane >> 3;          // group 0..7 = node slot
    const int sl   = lane & 7;           // channel octet
    const int wid  = (blockIdx.x * blockDim.x + threadIdx.x) >> 6;
    const int nw   = (gridDim.x * blockDim.x) >> 6;
    const float gc = temp[kcur];
    const float gp = temp[kcur - 1];

    for (int base = wid * 8; base < n; base += nw * 8) {
        int d = base + g;
        bool act = d < n;
        int dd = act ? d : (n - 1);
        int b = rowptr[dd];
        int en = act ? rowptr[dd + 1] : b;
        float di = dinv[dd];
        size_t rowoff = (size_t)dd * OUT_C + sl * 8;

        uint4 sraw = *(const uint4*)(cur + rowoff);
        float c0 = bfl(sraw.x), c1 = bfh(sraw.x), c2 = bfl(sraw.y), c3 = bfh(sraw.y),
              c4 = bfl(sraw.z), c5 = bfh(sraw.z), c6 = bfl(sraw.w), c7 = bfh(sraw.w);
        float s = di * di;
        float a0 = s * c0, a1 = s * c1, a2 = s * c2, a3 = s * c3,
              a4 = s * c4, a5 = s * c5, a6 = s * c6, a7 = s * c7;

        int i = b;
        for (; i + 2 <= en; i += 2) {
            int2 e0 = edges[i], e1 = edges[i + 1];
            uint4 r0 = *(const uint4*)(cur + (size_t)e0.x * OUT_C + sl * 8);
            uint4 r1 = *(const uint4*)(cur + (size_t)e1.x * OUT_C + sl * 8);
            float w0 = __int_as_float(e0.y), w1 = __int_as_float(e1.y);
            a0 = fmaf(w0, bfl(r0.x), a0); a1 = fmaf(w0, bfh(r0.x), a1);
            a2 = fmaf(w0, bfl(r0.y), a2); a3 = fmaf(w0, bfh(r0.y), a3);
            a4 = fmaf(w0, bfl(r0.z), a4); a5 = fmaf(w0, bfh(r0.z), a5);
            a6 = fmaf(w0, bfl(r0.w), a6); a7 = fmaf(w0, bfh(r0.w), a7);
            a0 = fmaf(w1, bfl(r1.x), a0); a1 = fmaf(w1, bfh(r1.x), a1);
            a2 = fmaf(w1, bfl(r1.y), a2); a3 = fmaf(w1, bfh(r1.y), a3);
            a4 = fmaf(w1, bfl(r1.z), a4); a5 = fmaf(w1, bfh(r1.z), a5);
            a6 = fmaf(w1, bfl(r1.w), a6); a7 = fmaf(w1, bfh(r1.w), a7);
        }
        if (i < en) {
            int2 e = edges[i];
            uint4 r0 = *(const uint4*)(cur + (size_t)e.x * OUT_C + sl * 8);
            float w0 = __int_as_float(e.y);
            a0 = fmaf(w0, bfl(r0.x), a0); a1 = fmaf(w0, bfh(r0.x), a1);
            a2 = fmaf(w0, bfl(r0.y), a2); a3 = fmaf(w0, bfh(r0.y), a3);
            a4 = fmaf(w0, bfl(r0.z), a4); a5 = fmaf(w0, bfh(r0.z), a5);
            a6 = fmaf(w0, bfl(r0.w), a6); a7 = fmaf(w0, bfh(r0.w), a7);
        }

        if (act) {
            if (do_nxt) {
                uint4 pk;
                pk.x = f2bf(a0) | (f2bf(a1) << 16);
                pk.y = f2bf(a2) | (f2bf(a3) << 16);
                pk.z = f2bf(a4) | (f2bf(a5) << 16);
                pk.w = f2bf(a6) | (f2bf(a7) << 16);
                *(uint4*)(nxt + rowoff) = pk;
            }
            if (do_rmw) {
                float4* op = (float4*)(out + rowoff);
                float4 v0 = op[0], v1 = op[1];
                v0.x += gp * c0 + gc * a0; v0.y += gp * c1 + gc * a1;
                v0.z += gp * c2 + gc * a2; v0.w += gp * c3 + gc * a3;
                v1.x += gp * c4 + gc * a4; v1.y += gp * c5 + gc * a5;
                v1.z += gp * c6 + gc * a6; v1.w += gp * c7 + gc * a7;
                op[0] = v0; op[1] = v1;
            }
        }
    }
}

// ---------------------------------------------------------------------------
extern "C" void kernel_launch(void* const* d_in, const int* in_sizes, int n_in,
                              void* d_out, int out_size, void* d_ws, size_t ws_size,
                              hipStream_t stream)
{
    const float* x    = (const float*)d_in[0];
    const int*   ei   = (const int*)d_in[1];
    const float* W1   = (const float*)d_in[2];
    const float* b1   = (const float*)d_in[3];
    const float* W2   = (const float*)d_in[4];
    const float* b2   = (const float*)d_in[5];
    const float* temp = (const float*)d_in[6];
    float* out = (float*)d_out;

    const int N = in_sizes[0] / IN_C;
    const int E = in_sizes[1] / 2;

    // workspace layout
    char* ws = (char*)d_ws;
    ushort* bufA  = (ushort*)ws;                       // N*64 bf16
    ushort* bufB  = bufA + (size_t)N * OUT_C;          // N*64 bf16
    int2*   edges = (int2*)(bufB + (size_t)N * OUT_C); // E int2
    ushort* W1b   = (ushort*)(edges + E);
    ushort* w2kt  = W1b + HID_C * IN_C;
    float*  dinv  = (float*)(w2kt + OUT_C * HID_C);
    int*    cnt    = (int*)(dinv + N);
    int*    fill   = cnt + N;
    int*    rowptr = fill + N;
    int*    bsum   = rowptr + (N + 16);

    const int nbN = (N + 255) / 256;
    const int nbE = (E + 255) / 256;

    k_init   <<<nbN, 256, 0, stream>>>(cnt, fill, N);
    k_hist   <<<nbE, 256, 0, stream>>>(ei, cnt, E);
    k_dinv   <<<nbN, 256, 0, stream>>>(cnt, dinv, N);
    k_scan1  <<<nbN, 256, 0, stream>>>(cnt, rowptr, bsum, N);
    k_scan2  <<<1,   512, 0, stream>>>(bsum, nbN);
    k_scan3  <<<nbN, 256, 0, stream>>>(rowptr, bsum, N);
    k_scatter<<<nbE, 256, 0, stream>>>(ei, dinv, rowptr, fill, edges, E);
    k_cvt    <<<(HID_C * IN_C + 255) / 256, 256, 0, stream>>>(W1, W1b, HID_C * IN_C);
    k_cvtw2  <<<(OUT_C * HID_C + 255) / 256, 256, 0, stream>>>(W2, w2kt);

    k_mlp<<<(N + 63) / 64, 256, 0, stream>>>(x, W1b, b1, w2kt, b2, temp, bufA, out, N);

    ushort* cur = bufA;
    ushort* nxt = bufB;
    for (int k = 1; k <= KSTEPS; ++k) {
        int do_rmw = (k % 2 == 0) ? 1 : 0;
        int do_nxt = (k < KSTEPS) ? 1 : 0;
        k_prop<<<2048, 256, 0, stream>>>(rowptr, edges, cur, nxt, out, dinv,
                                         temp, k, do_rmw, do_nxt, N);
        ushort* t = cur; cur = nxt; nxt = t;
    }
}

// Round 6
// 583.112 us; speedup vs baseline: 1.4280x; 1.2977x over previous
//
#include <hip/hip_runtime.h>

#define IN_C   512
#define HID_C  256
#define OUT_C  64
#define KSTEPS 10

typedef __attribute__((ext_vector_type(8))) short bf16x8;
typedef __attribute__((ext_vector_type(4))) float f32x4;

__device__ __forceinline__ uint f2bf(float f) {
    uint u = __float_as_uint(f);
    return (u + 0x7fffu + ((u >> 16) & 1u)) >> 16;   // RNE to bf16
}
__device__ __forceinline__ float bfl(uint u) { return __uint_as_float(u << 16); }
__device__ __forceinline__ float bfh(uint u) { return __uint_as_float(u & 0xffff0000u); }

// ---------------------------------------------------------------------------
// CSR build: histogram by dst, exclusive scan, scatter (src, norm) pairs.
// ---------------------------------------------------------------------------
__global__ void k_init(int* __restrict__ cnt, int* __restrict__ fill, int n) {
    int i = blockIdx.x * blockDim.x + threadIdx.x;
    if (i < n) { cnt[i] = 0; fill[i] = 0; }
}

__global__ void k_hist(const int* __restrict__ ei, int* __restrict__ cnt, int E) {
    int e = blockIdx.x * blockDim.x + threadIdx.x;
    if (e < E) atomicAdd(&cnt[ei[E + e]], 1);
}

__global__ void k_dinv(const int* __restrict__ cnt, float* __restrict__ dinv, int n) {
    int i = blockIdx.x * blockDim.x + threadIdx.x;
    if (i < n) dinv[i] = rsqrtf((float)cnt[i] + 1.0f);   // deg includes self loop
}

__global__ void k_scan1(const int* __restrict__ cnt, int* __restrict__ rowptr,
                        int* __restrict__ bsum, int n) {
    __shared__ int sh[256];
    int i = blockIdx.x * 256 + threadIdx.x;
    int v = (i < n) ? cnt[i] : 0;
    sh[threadIdx.x] = v;
    __syncthreads();
    for (int off = 1; off < 256; off <<= 1) {
        int t = (threadIdx.x >= off) ? sh[threadIdx.x - off] : 0;
        __syncthreads();
        sh[threadIdx.x] += t;
        __syncthreads();
    }
    if (i < n) rowptr[i + 1] = sh[threadIdx.x];
    if (threadIdx.x == 255) bsum[blockIdx.x] = sh[255];
}

__global__ void k_scan2(int* __restrict__ bsum, int nb) {
    __shared__ int sh[512];
    int t = threadIdx.x;
    int v = (t < nb) ? bsum[t] : 0;
    sh[t] = v;
    __syncthreads();
    for (int off = 1; off < 512; off <<= 1) {
        int u = (t >= off) ? sh[t - off] : 0;
        __syncthreads();
        sh[t] += u;
        __syncthreads();
    }
    int ex = (t == 0) ? 0 : sh[t - 1];
    if (t < nb) bsum[t] = ex;
}

__global__ void k_scan3(int* __restrict__ rowptr, const int* __restrict__ bsum, int n) {
    int i = blockIdx.x * blockDim.x + threadIdx.x;
    if (i < n) rowptr[i + 1] += bsum[i >> 8];
    if (i == 0) rowptr[0] = 0;
}

__global__ void k_scatter(const int* __restrict__ ei, const float* __restrict__ dinv,
                          const int* __restrict__ rowptr, int* __restrict__ fill,
                          int2* __restrict__ edges, int E) {
    int e = blockIdx.x * blockDim.x + threadIdx.x;
    if (e < E) {
        int s = ei[e], d = ei[E + e];
        float nv = dinv[s] * dinv[d];
        int pos = rowptr[d] + atomicAdd(&fill[d], 1);
        edges[pos] = make_int2(s, __float_as_int(nv));
    }
}

// W1 -> bf16 "LDS image": 8 k-chunks of [256 rows][8 blocks of 16B], block
// index pre-XOR-swizzled (bd = bq ^ (row&7)) so a LINEAR global_load_lds copy
// produces the swizzled LDS layout (G21: pre-swizzle source, linear dest).
__global__ void k_prepw1(const float* __restrict__ W1, ushort* __restrict__ w1img) {
    int i = blockIdx.x * blockDim.x + threadIdx.x;
    if (i < HID_C * IN_C) {
        int t  = i >> 14;          // k-chunk 0..7
        int rm = i & 16383;
        int nn = rm >> 6;          // row 0..255
        int bd = (rm >> 3) & 7;    // dest 16B block
        int j  = rm & 7;
        int bq = bd ^ (nn & 7);    // source block (involution)
        w1img[i] = (ushort)f2bf(W1[nn * IN_C + t * 64 + bq * 8 + j]);
    }
}

// W2 -> bf16, k-block-major: w2kt[kb][n][8], kb = hidden/8. Coalesced B-frag reads.
__global__ void k_cvtw2(const float* __restrict__ W2, ushort* __restrict__ w2kt) {
    int i = blockIdx.x * blockDim.x + threadIdx.x;
    if (i < OUT_C * HID_C) {
        int o = i >> 8;       // W2 row (out channel) 0..63
        int c = i & 255;      // hidden idx 0..255
        int kb = c >> 3, j = c & 7;
        w2kt[((size_t)(kb * 64 + o)) * 8 + j] = (ushort)f2bf(W2[i]);
    }
}

// ---------------------------------------------------------------------------
// Fused MFMA MLP: h2 = relu(x@W1^T + b1) @ W2^T + b2  (bf16 in, fp32 accum)
// 4 waves, BM=64. Stage1: wave w -> hidden cols [64w,64w+64), BK=64.
// W1 staged via global_load_lds (zero-VGPR async DMA, pre-swizzled image);
// x staged manually (f32->bf16 cvt). h1 -> LDS bf16 swizzled. Stage2: B
// fragments from w2kt (coalesced global, L2-resident 32KB).
// NO register prefetch: rounds 4/5 proved it spills (WRITE 517/422 MB).
// ---------------------------------------------------------------------------
__global__ __launch_bounds__(256, 4) void k_mlp(
    const float* __restrict__ x, const ushort* __restrict__ w1img,
    const float* __restrict__ b1, const ushort* __restrict__ w2kt,
    const float* __restrict__ b2, const float* __restrict__ temp,
    ushort* __restrict__ h, float* __restrict__ out, int n)
{
    __shared__ uint4 smem4[2560];            // 40 KB
    char* smem = (char*)smem4;
    // phase 1: w1s = smem[0 .. 32K)  [256 rows][128 B]   xs = smem[32K..40K)
    // phase 2: h1s = smem[0 .. 32K)  [64 rows][512 B]

    const int tid = threadIdx.x;
    const int lane = tid & 63;
    const int w    = tid >> 6;        // wave 0..3
    const int l15  = lane & 15;
    const int l4   = lane >> 4;       // 0..3
    const int row0 = blockIdx.x * 64;

    f32x4 acc[4][4];                  // [rf][nf]
#pragma unroll
    for (int i = 0; i < 4; ++i)
#pragma unroll
        for (int j = 0; j < 4; ++j) acc[i][j] = (f32x4){0.f, 0.f, 0.f, 0.f};

    for (int k0 = 0; k0 < IN_C; k0 += 64) {
        // W1 chunk: linear 32KB async copy, zero VGPRs (image is pre-swizzled)
        const char* w1c = (const char*)w1img + (size_t)(k0 >> 6) * 32768;
#pragma unroll
        for (int it = 0; it < 8; ++it) {
            int base = it * 4096 + w * 1024;           // wave-uniform LDS byte
            __builtin_amdgcn_global_load_lds(
                (const __attribute__((address_space(1))) void*)(w1c + base + lane * 16),
                (__attribute__((address_space(3))) void*)(smem + base),
                16, 0, 0);
        }
        // x tile: 64 rows x 64 k, f32 -> bf16, swizzled, at 32K
#pragma unroll
        for (int it = 0; it < 4; ++it) {
            int f  = tid + it * 256;          // float4 slot 0..1023
            int r  = f >> 4;                  // row 0..63
            int c4 = f & 15;                  // float4 idx within row
            int gr = row0 + r; if (gr >= n) gr = n - 1;
            float4 v = *(const float4*)(x + (size_t)gr * IN_C + k0 + c4 * 4);
            uint p0 = f2bf(v.x) | (f2bf(v.y) << 16);
            uint p1 = f2bf(v.z) | (f2bf(v.w) << 16);
            int boff = (c4 * 8) ^ ((r & 7) << 4);
            *(uint2*)(smem + 32768 + r * 128 + boff) = make_uint2(p0, p1);
        }
        __syncthreads();

#pragma unroll
        for (int kk = 0; kk < 2; ++kk) {
            bf16x8 af[4], bfr[4];
            int kb = kk * 4 + l4;             // 16B-block in k
#pragma unroll
            for (int rf = 0; rf < 4; ++rf) {
                int r = rf * 16 + l15;
                af[rf] = *(const bf16x8*)(smem + 32768 + r * 128 + ((kb ^ (r & 7)) << 4));
            }
#pragma unroll
            for (int nf = 0; nf < 4; ++nf) {
                int nn = w * 64 + nf * 16 + l15;
                bfr[nf] = *(const bf16x8*)(smem + nn * 128 + ((kb ^ (nn & 7)) << 4));
            }
#pragma unroll
            for (int rf = 0; rf < 4; ++rf)
#pragma unroll
                for (int nf = 0; nf < 4; ++nf)
                    acc[rf][nf] = __builtin_amdgcn_mfma_f32_16x16x32_bf16(
                        af[rf], bfr[nf], acc[rf][nf], 0, 0, 0);
        }
        __syncthreads();
    }

    // bias + relu -> h1s bf16 swizzled at 0 (overwrites w1s; barrier done)
    float bias1[4];
#pragma unroll
    for (int nf = 0; nf < 4; ++nf) bias1[nf] = b1[w * 64 + nf * 16 + l15];
#pragma unroll
    for (int rf = 0; rf < 4; ++rf)
#pragma unroll
        for (int nf = 0; nf < 4; ++nf)
#pragma unroll
            for (int j = 0; j < 4; ++j) {
                int r = rf * 16 + l4 * 4 + j;
                int c = w * 64 + nf * 16 + l15;
                float v = fmaxf(acc[rf][nf][j] + bias1[nf], 0.f);
                int byte = r * 512 + ((((c >> 3) ^ (r & 7))) << 4) + (c & 7) * 2;
                *(ushort*)(smem + byte) = (ushort)f2bf(v);
            }
    __syncthreads();

    // stage 2: rows slab per wave, K=256; B fragments from w2kt (coalesced)
    f32x4 acc2[4];
#pragma unroll
    for (int nf = 0; nf < 4; ++nf) acc2[nf] = (f32x4){0.f, 0.f, 0.f, 0.f};
#pragma unroll
    for (int kk = 0; kk < 8; ++kk) {
        int r = w * 16 + l15;
        int kb = kk * 4 + l4;
        bf16x8 a = *(const bf16x8*)(smem + r * 512 + ((kb ^ (r & 7)) << 4));
#pragma unroll
        for (int nf = 0; nf < 4; ++nf) {
            bf16x8 bb = *(const bf16x8*)(w2kt + ((size_t)kb * 64 + nf * 16 + l15) * 8);
            acc2[nf] = __builtin_amdgcn_mfma_f32_16x16x32_bf16(a, bb, acc2[nf], 0, 0, 0);
        }
    }

    float t0 = temp[0];
#pragma unroll
    for (int nf = 0; nf < 4; ++nf) {
        int c = nf * 16 + l15;
        float bias = b2[c];
#pragma unroll
        for (int j = 0; j < 4; ++j) {
            int gr = row0 + w * 16 + l4 * 4 + j;
            if (gr < n) {
                float v = acc2[nf][j] + bias;
                h[(size_t)gr * OUT_C + c]   = (ushort)f2bf(v);
                out[(size_t)gr * OUT_C + c] = t0 * v;
            }
        }
    }
}

// ---------------------------------------------------------------------------
// One propagation step: one 8-lane GROUP per dst node (8 nodes/wave).
// Unroll x4: 4 gathers in flight. No cross-lane reduction. Even steps fold
// out += gp*cur + gc*acc (cur row already loaded for the self-loop term).
// ---------------------------------------------------------------------------
__global__ __launch_bounds__(256) void k_prop(
    const int* __restrict__ rowptr, const int2* __restrict__ edges,
    const ushort* __restrict__ cur, ushort* __restrict__ nxt,
    float* __restrict__ out, const float* __restrict__ dinv,
    const float* __restrict__ temp, int kcur, int do_rmw, int do_nxt, int n)
{
    const int lane = threadIdx.x & 63;
    const int g    = lane >> 3;          // group 0..7 = node slot
    const int sl   = lane & 7;           // channel octet
    const int wid  = (blockIdx.x * blockDim.x + threadIdx.x) >> 6;
    const int nw   = (gridDim.x * blockDim.x) >> 6;
    const float gc = temp[kcur];
    const float gp = temp[kcur - 1];

    for (int base = wid * 8; base < n; base += nw * 8) {
        int d = base + g;
        bool act = d < n;
        int dd = act ? d : (n - 1);
        int b = rowptr[dd];
        int en = act ? rowptr[dd + 1] : b;
        float di = dinv[dd];
        size_t rowoff = (size_t)dd * OUT_C + sl * 8;

        uint4 sraw = *(const uint4*)(cur + rowoff);
        float c0 = bfl(sraw.x), c1 = bfh(sraw.x), c2 = bfl(sraw.y), c3 = bfh(sraw.y),
              c4 = bfl(sraw.z), c5 = bfh(sraw.z), c6 = bfl(sraw.w), c7 = bfh(sraw.w);
        float s = di * di;
        float a0 = s * c0, a1 = s * c1, a2 = s * c2, a3 = s * c3,
              a4 = s * c4, a5 = s * c5, a6 = s * c6, a7 = s * c7;

        int i = b;
        for (; i + 4 <= en; i += 4) {
            int2 e0 = edges[i], e1 = edges[i + 1], e2 = edges[i + 2], e3 = edges[i + 3];
            uint4 r0 = *(const uint4*)(cur + (size_t)e0.x * OUT_C + sl * 8);
            uint4 r1 = *(const uint4*)(cur + (size_t)e1.x * OUT_C + sl * 8);
            uint4 r2 = *(const uint4*)(cur + (size_t)e2.x * OUT_C + sl * 8);
            uint4 r3 = *(const uint4*)(cur + (size_t)e3.x * OUT_C + sl * 8);
            float w0 = __int_as_float(e0.y), w1 = __int_as_float(e1.y);
            float w2 = __int_as_float(e2.y), w3 = __int_as_float(e3.y);
            a0 = fmaf(w0, bfl(r0.x), a0); a1 = fmaf(w0, bfh(r0.x), a1);
            a2 = fmaf(w0, bfl(r0.y), a2); a3 = fmaf(w0, bfh(r0.y), a3);
            a4 = fmaf(w0, bfl(r0.z), a4); a5 = fmaf(w0, bfh(r0.z), a5);
            a6 = fmaf(w0, bfl(r0.w), a6); a7 = fmaf(w0, bfh(r0.w), a7);
            a0 = fmaf(w1, bfl(r1.x), a0); a1 = fmaf(w1, bfh(r1.x), a1);
            a2 = fmaf(w1, bfl(r1.y), a2); a3 = fmaf(w1, bfh(r1.y), a3);
            a4 = fmaf(w1, bfl(r1.z), a4); a5 = fmaf(w1, bfh(r1.z), a5);
            a6 = fmaf(w1, bfl(r1.w), a6); a7 = fmaf(w1, bfh(r1.w), a7);
            a0 = fmaf(w2, bfl(r2.x), a0); a1 = fmaf(w2, bfh(r2.x), a1);
            a2 = fmaf(w2, bfl(r2.y), a2); a3 = fmaf(w2, bfh(r2.y), a3);
            a4 = fmaf(w2, bfl(r2.z), a4); a5 = fmaf(w2, bfh(r2.z), a5);
            a6 = fmaf(w2, bfl(r2.w), a6); a7 = fmaf(w2, bfh(r2.w), a7);
            a0 = fmaf(w3, bfl(r3.x), a0); a1 = fmaf(w3, bfh(r3.x), a1);
            a2 = fmaf(w3, bfl(r3.y), a2); a3 = fmaf(w3, bfh(r3.y), a3);
            a4 = fmaf(w3, bfl(r3.z), a4); a5 = fmaf(w3, bfh(r3.z), a5);
            a6 = fmaf(w3, bfl(r3.w), a6); a7 = fmaf(w3, bfh(r3.w), a7);
        }
        for (; i < en; ++i) {
            int2 e = edges[i];
            uint4 r0 = *(const uint4*)(cur + (size_t)e.x * OUT_C + sl * 8);
            float w0 = __int_as_float(e.y);
            a0 = fmaf(w0, bfl(r0.x), a0); a1 = fmaf(w0, bfh(r0.x), a1);
            a2 = fmaf(w0, bfl(r0.y), a2); a3 = fmaf(w0, bfh(r0.y), a3);
            a4 = fmaf(w0, bfl(r0.z), a4); a5 = fmaf(w0, bfh(r0.z), a5);
            a6 = fmaf(w0, bfl(r0.w), a6); a7 = fmaf(w0, bfh(r0.w), a7);
        }

        if (act) {
            if (do_nxt) {
                uint4 pk;
                pk.x = f2bf(a0) | (f2bf(a1) << 16);
                pk.y = f2bf(a2) | (f2bf(a3) << 16);
                pk.z = f2bf(a4) | (f2bf(a5) << 16);
                pk.w = f2bf(a6) | (f2bf(a7) << 16);
                *(uint4*)(nxt + rowoff) = pk;
            }
            if (do_rmw) {
                float4* op = (float4*)(out + rowoff);
                float4 v0 = op[0], v1 = op[1];
                v0.x += gp * c0 + gc * a0; v0.y += gp * c1 + gc * a1;
                v0.z += gp * c2 + gc * a2; v0.w += gp * c3 + gc * a3;
                v1.x += gp * c4 + gc * a4; v1.y += gp * c5 + gc * a5;
                v1.z += gp * c6 + gc * a6; v1.w += gp * c7 + gc * a7;
                op[0] = v0; op[1] = v1;
            }
        }
    }
}

// ---------------------------------------------------------------------------
extern "C" void kernel_launch(void* const* d_in, const int* in_sizes, int n_in,
                              void* d_out, int out_size, void* d_ws, size_t ws_size,
                              hipStream_t stream)
{
    const float* x    = (const float*)d_in[0];
    const int*   ei   = (const int*)d_in[1];
    const float* W1   = (const float*)d_in[2];
    const float* b1   = (const float*)d_in[3];
    const float* W2   = (const float*)d_in[4];
    const float* b2   = (const float*)d_in[5];
    const float* temp = (const float*)d_in[6];
    float* out = (float*)d_out;

    const int N = in_sizes[0] / IN_C;
    const int E = in_sizes[1] / 2;

    // workspace layout
    char* ws = (char*)d_ws;
    ushort* bufA  = (ushort*)ws;                       // N*64 bf16
    ushort* bufB  = bufA + (size_t)N * OUT_C;          // N*64 bf16
    int2*   edges = (int2*)(bufB + (size_t)N * OUT_C); // E int2
    ushort* w1img = (ushort*)(edges + E);
    ushort* w2kt  = w1img + HID_C * IN_C;
    float*  dinv  = (float*)(w2kt + OUT_C * HID_C);
    int*    cnt    = (int*)(dinv + N);
    int*    fill   = cnt + N;
    int*    rowptr = fill + N;
    int*    bsum   = rowptr + (N + 16);

    const int nbN = (N + 255) / 256;
    const int nbE = (E + 255) / 256;

    k_init   <<<nbN, 256, 0, stream>>>(cnt, fill, N);
    k_hist   <<<nbE, 256, 0, stream>>>(ei, cnt, E);
    k_dinv   <<<nbN, 256, 0, stream>>>(cnt, dinv, N);
    k_scan1  <<<nbN, 256, 0, stream>>>(cnt, rowptr, bsum, N);
    k_scan2  <<<1,   512, 0, stream>>>(bsum, nbN);
    k_scan3  <<<nbN, 256, 0, stream>>>(rowptr, bsum, N);
    k_scatter<<<nbE, 256, 0, stream>>>(ei, dinv, rowptr, fill, edges, E);
    k_prepw1 <<<(HID_C * IN_C + 255) / 256, 256, 0, stream>>>(W1, w1img);
    k_cvtw2  <<<(OUT_C * HID_C + 255) / 256, 256, 0, stream>>>(W2, w2kt);

    k_mlp<<<(N + 63) / 64, 256, 0, stream>>>(x, w1img, b1, w2kt, b2, temp, bufA, out, N);

    ushort* cur = bufA;
    ushort* nxt = bufB;
    for (int k = 1; k <= KSTEPS; ++k) {
        int do_rmw = (k % 2 == 0) ? 1 : 0;
        int do_nxt = (k < KSTEPS) ? 1 : 0;
        k_prop<<<2048, 256, 0, stream>>>(rowptr, edges, cur, nxt, out, dinv,
                                         temp, k, do_rmw, do_nxt, N);
        ushort* t = cur; cur = nxt; nxt = t;
    }
}